// Round 1
// baseline (199.891 us; speedup 1.0000x reference)
//
#include <hip/hip_runtime.h>
#include <hip/hip_bf16.h>

// ---------------- types ----------------
typedef float f32x4 __attribute__((ext_vector_type(4)));
typedef __bf16 v8bf __attribute__((ext_vector_type(8)));
typedef unsigned short ushortx4 __attribute__((ext_vector_type(4)));
typedef unsigned short ushortx8 __attribute__((ext_vector_type(8)));

#define NIMG 16
#define CCH  256
#define HWP  1600
#define PIT  776   // stage pitch (bf16 elems): 1552B, 16B aligned

__device__ __forceinline__ unsigned short f2bf(float f) {
  unsigned int u = __builtin_bit_cast(unsigned int, f);
  u = (u + 0x7FFFu + ((u >> 16) & 1u)) >> 16;
  return (unsigned short)u;
}

__device__ __forceinline__ f32x4 mfma16(v8bf a, v8bf b, f32x4 c) {
  return __builtin_amdgcn_mfma_f32_16x16x32_bf16(a, b, c, 0, 0, 0);
}

// ---------------- kernel A: weight->bf16 + PE table ----------------
__global__ void prep_kernel(const float* __restrict__ qkv_w,
                            float* __restrict__ pe,
                            unsigned short* __restrict__ w_bf) {
  int tid = blockIdx.x * blockDim.x + threadIdx.x;
  int nthr = gridDim.x * blockDim.x;
  for (int i = tid; i < 768 * 256; i += nthr) w_bf[i] = f2bf(qkv_w[i]);
  const float c1 = 9.210340371976184f / 64.f;  // ln(10000)/64
  for (int i = tid; i < HWP * 256; i += nthr) {
    int p = i >> 8, c = i & 255;
    int j = p % 40, ii = p / 40;             // x = j (col), y = ii (row)
    int tt = c & 63;
    float omega = expf(-(float)tt * c1);
    float coord = (c < 128) ? (float)j : (float)ii;
    float a = coord * omega;
    pe[i] = ((c & 64) == 0) ? sinf(a) : cosf(a);
  }
}

// ---------------- kernel B: LN + QKV GEMM + PE, writes q,k,[v^T] bf16 ----------------
__global__ __launch_bounds__(512, 2) void ln_qkv_kernel(
    const float* __restrict__ x, const float* __restrict__ ln_w, const float* __restrict__ ln_b,
    const unsigned short* __restrict__ w_bf, const float* __restrict__ qkv_b,
    const float* __restrict__ pe,
    unsigned short* __restrict__ q_ws, unsigned short* __restrict__ k_ws,
    unsigned short* __restrict__ v_t) {
  __shared__ unsigned short buf[64][PIT];          // A-tile (cols 0..255) then qkv stage (0..767)
  __shared__ float red_s[8][64], red_q[8][64];
  __shared__ float mu_s[64], rs_s[64];

  int t = threadIdx.x;
  int n = blockIdx.x / 25, pt = blockIdx.x % 25;
  int pix0 = pt * 64;
  int p = t & 63, g = t >> 6;
  const float* xb = x + (size_t)n * CCH * HWP + pix0;

  // pass 1: LN stats (x kept in registers)
  float xv[32];
  float sum = 0.f, sq = 0.f;
#pragma unroll
  for (int i = 0; i < 32; ++i) {
    float v = xb[(size_t)(g * 32 + i) * HWP + p];
    xv[i] = v; sum += v; sq += v * v;
  }
  red_s[g][p] = sum; red_q[g][p] = sq;
  __syncthreads();
  if (t < 64) {
    float s = 0.f, q2 = 0.f;
#pragma unroll
    for (int gg = 0; gg < 8; ++gg) { s += red_s[gg][t]; q2 += red_q[gg][t]; }
    float mu = s * (1.f / 256.f);
    float var = q2 * (1.f / 256.f) - mu * mu;
    mu_s[t] = mu;
    rs_s[t] = rsqrtf(var + 1e-5f);
  }
  __syncthreads();
  float mu = mu_s[p], rs = rs_s[p];
#pragma unroll
  for (int i = 0; i < 32; ++i) {
    int cc = g * 32 + i;
    float xn = (xv[i] - mu) * rs * ln_w[cc] + ln_b[cc];
    buf[p][cc] = f2bf(xn);
  }
  __syncthreads();

  // GEMM: 64 pixels x 768 outs, K=256; 8 waves each own 96 output cols
  int w = t >> 6, l = t & 63, lr = l & 15, lg = l >> 4;
  int colbase = w * 96;
  f32x4 acc[4][6];
#pragma unroll
  for (int mi = 0; mi < 4; ++mi)
#pragma unroll
    for (int nf = 0; nf < 6; ++nf) acc[mi][nf] = (f32x4){0.f, 0.f, 0.f, 0.f};

#pragma unroll
  for (int ks = 0; ks < 8; ++ks) {
    v8bf aF[4];
#pragma unroll
    for (int mi = 0; mi < 4; ++mi)
      aF[mi] = *(const v8bf*)&buf[mi * 16 + lr][ks * 32 + lg * 8];
#pragma unroll
    for (int nf = 0; nf < 6; ++nf) {
      int o = colbase + nf * 16 + lr;
      v8bf bF = *(const v8bf*)&w_bf[o * 256 + ks * 32 + lg * 8];
#pragma unroll
      for (int mi = 0; mi < 4; ++mi) acc[mi][nf] = mfma16(aF[mi], bF, acc[mi][nf]);
    }
  }
  __syncthreads();  // A-tile dead; reuse buf as stage

  // epilogue: +bias, +PE on q/k, bf16 -> stage[pixel][out]
#pragma unroll
  for (int nf = 0; nf < 6; ++nf) {
    int o = colbase + nf * 16 + lr;
    float bias = qkv_b[o];
#pragma unroll
    for (int mi = 0; mi < 4; ++mi) {
#pragma unroll
      for (int r = 0; r < 4; ++r) {
        int prow = mi * 16 + lg * 4 + r;
        float val = acc[mi][nf][r] + bias;
        if (o < 512) val += pe[(pix0 + prow) * 256 + (o & 255)];
        buf[prow][o] = f2bf(val);
      }
    }
  }
  __syncthreads();

  // coalesced write-out: q,k as [n][p][c]; v transposed as [n][d][p]
  size_t qbase = ((size_t)n * HWP + pix0) * 256;
#pragma unroll
  for (int it = 0; it < 8; ++it) {
    int id = t + it * 512;
    int row = id >> 6, cc = (id & 63) * 4;
    ushortx4 qv, kv;
#pragma unroll
    for (int r4 = 0; r4 < 4; ++r4) {
      qv[r4] = buf[row][cc + r4];
      kv[r4] = buf[row][256 + cc + r4];
    }
    *(ushortx4*)&q_ws[qbase + row * 256 + cc] = qv;
    *(ushortx4*)&k_ws[qbase + row * 256 + cc] = kv;
  }
#pragma unroll
  for (int it = 0; it < 8; ++it) {
    int id = t + it * 512;
    int pc = id & 15, d = id >> 4;
    ushortx4 vv;
#pragma unroll
    for (int r4 = 0; r4 < 4; ++r4) vv[r4] = buf[pc * 4 + r4][512 + d];
    *(ushortx4*)&v_t[((size_t)n * 256 + d) * HWP + pix0 + pc * 4] = vv;
  }
}

// ---------------- kernel C: flash attention + residual epilogue ----------------
__global__ __launch_bounds__(256, 2) void attn_kernel(
    const unsigned short* __restrict__ q_ws, const unsigned short* __restrict__ k_ws,
    const unsigned short* __restrict__ v_t, const float* __restrict__ x,
    const float* __restrict__ gamma, float* __restrict__ out) {
  __shared__ unsigned short k_lds[64][264];   // 33,792 B
  __shared__ unsigned short v_lds[256][72];   // 36,864 B  (v^T: [d][kv])
  __shared__ unsigned short p_lds[4][16][72]; //  9,216 B

  int t = threadIdx.x;
  int n = blockIdx.x / 25, qt = blockIdx.x % 25;
  int q0 = qt * 64;
  int w = t >> 6, l = t & 63, lr = l & 15, lg = l >> 4;

  // Q fragments in registers (wave w owns q rows q0+w*16 .. +15)
  v8bf aq[8];
  size_t qrow = ((size_t)n * HWP + q0 + w * 16 + lr) * 256;
#pragma unroll
  for (int ks = 0; ks < 8; ++ks)
    aq[ks] = *(const v8bf*)&q_ws[qrow + ks * 32 + lg * 8];

  f32x4 acc[16];
#pragma unroll
  for (int od = 0; od < 16; ++od) acc[od] = (f32x4){0.f, 0.f, 0.f, 0.f};
  float m_run[4] = {-1e30f, -1e30f, -1e30f, -1e30f};
  float l_run[4] = {0.f, 0.f, 0.f, 0.f};

  for (int kt = 0; kt < 25; ++kt) {
    int kv0 = kt * 64;
    // stage K tile [64][256]
#pragma unroll
    for (int it = 0; it < 8; ++it) {
      int id = t + it * 256;
      int row = id >> 5, cc = (id & 31) * 8;
      *(ushortx8*)&k_lds[row][cc] =
          *(const ushortx8*)&k_ws[((size_t)n * HWP + kv0 + row) * 256 + cc];
    }
    // stage V^T tile [256][64]
#pragma unroll
    for (int it = 0; it < 8; ++it) {
      int id = t + it * 256;
      int d = id >> 3, cc = (id & 7) * 8;
      *(ushortx8*)&v_lds[d][cc] =
          *(const ushortx8*)&v_t[((size_t)n * 256 + d) * HWP + kv0 + cc];
    }
    __syncthreads();

    // S = Q K^T  (per wave: 16 q rows x 64 kv cols)
    f32x4 s[4];
#pragma unroll
    for (int kf = 0; kf < 4; ++kf) s[kf] = (f32x4){0.f, 0.f, 0.f, 0.f};
#pragma unroll
    for (int ks = 0; ks < 8; ++ks) {
#pragma unroll
      for (int kf = 0; kf < 4; ++kf) {
        v8bf bk = *(const v8bf*)&k_lds[kf * 16 + lr][ks * 32 + lg * 8];
        s[kf] = mfma16(aq[ks], bk, s[kf]);
      }
    }

    // online softmax (rows = lg*4+r, reduce over 16 lanes of the group)
    float pv[4][4];
    float alpha[4];
#pragma unroll
    for (int r = 0; r < 4; ++r) {
      float mx = fmaxf(fmaxf(s[0][r], s[1][r]), fmaxf(s[2][r], s[3][r])) * 0.0625f;
      mx = fmaxf(mx, __shfl_xor(mx, 1));
      mx = fmaxf(mx, __shfl_xor(mx, 2));
      mx = fmaxf(mx, __shfl_xor(mx, 4));
      mx = fmaxf(mx, __shfl_xor(mx, 8));
      float mnew = fmaxf(m_run[r], mx);
      alpha[r] = __expf(m_run[r] - mnew);
      float ps = 0.f;
#pragma unroll
      for (int kf = 0; kf < 4; ++kf) {
        float e = __expf(s[kf][r] * 0.0625f - mnew);
        pv[kf][r] = e; ps += e;
      }
      ps += __shfl_xor(ps, 1);
      ps += __shfl_xor(ps, 2);
      ps += __shfl_xor(ps, 4);
      ps += __shfl_xor(ps, 8);
      l_run[r] = l_run[r] * alpha[r] + ps;
      m_run[r] = mnew;
    }
#pragma unroll
    for (int od = 0; od < 16; ++od)
#pragma unroll
      for (int r = 0; r < 4; ++r) acc[od][r] *= alpha[r];

    // P -> LDS (bf16), per-wave private tile
#pragma unroll
    for (int kf = 0; kf < 4; ++kf)
#pragma unroll
      for (int r = 0; r < 4; ++r)
        p_lds[w][lg * 4 + r][kf * 16 + lr] = f2bf(pv[kf][r]);
    __syncthreads();

    // O += P V
#pragma unroll
    for (int ks2 = 0; ks2 < 2; ++ks2) {
      v8bf ap = *(const v8bf*)&p_lds[w][lr][ks2 * 32 + lg * 8];
#pragma unroll
      for (int od = 0; od < 16; ++od) {
        v8bf bv = *(const v8bf*)&v_lds[od * 16 + lr][ks2 * 32 + lg * 8];
        acc[od] = mfma16(ap, bv, acc[od]);
      }
    }
    __syncthreads();
  }

  // epilogue: out = x + gamma * (O / l)
  float gm = gamma[0];
  float inv[4];
#pragma unroll
  for (int r = 0; r < 4; ++r) inv[r] = 1.f / l_run[r];
#pragma unroll
  for (int od = 0; od < 16; ++od) {
    int d = od * 16 + lr;
    size_t base = ((size_t)n * 256 + d) * HWP + q0 + w * 16 + lg * 4;
    f32x4 xvv = *(const f32x4*)&x[base];
    f32x4 ov;
#pragma unroll
    for (int r = 0; r < 4; ++r) ov[r] = xvv[r] + gm * (acc[od][r] * inv[r]);
    *(f32x4*)&out[base] = ov;
  }
}

// ---------------- launcher ----------------
extern "C" void kernel_launch(void* const* d_in, const int* in_sizes, int n_in,
                              void* d_out, int out_size, void* d_ws, size_t ws_size,
                              hipStream_t stream) {
  const float* x     = (const float*)d_in[0];
  const float* ln_w  = (const float*)d_in[1];
  const float* ln_b  = (const float*)d_in[2];
  const float* qkv_w = (const float*)d_in[3];
  const float* qkv_b = (const float*)d_in[4];
  const float* gamma = (const float*)d_in[5];
  float* out = (float*)d_out;

  char* ws = (char*)d_ws;
  unsigned short* w_bf = (unsigned short*)ws;            //   393,216 B
  float*          pe   = (float*)(ws + 393216);          // 1,638,400 B
  unsigned short* q_ws = (unsigned short*)(ws + 2031616);  // 13,107,200 B
  unsigned short* k_ws = (unsigned short*)(ws + 15138816); // 13,107,200 B
  unsigned short* v_t  = (unsigned short*)(ws + 28246016); // 13,107,200 B

  hipLaunchKernelGGL(prep_kernel, dim3(384), dim3(256), 0, stream, qkv_w, pe, w_bf);
  hipLaunchKernelGGL(ln_qkv_kernel, dim3(400), dim3(512), 0, stream,
                     x, ln_w, ln_b, w_bf, qkv_b, pe, q_ws, k_ws, v_t);
  hipLaunchKernelGGL(attn_kernel, dim3(400), dim3(256), 0, stream,
                     q_ws, k_ws, v_t, x, gamma, out);
}

// Round 2
// 191.366 us; speedup vs baseline: 1.0445x; 1.0445x over previous
//
#include <hip/hip_runtime.h>
#include <hip/hip_bf16.h>

// ---------------- types ----------------
typedef float f32x4 __attribute__((ext_vector_type(4)));
typedef float f32x16 __attribute__((ext_vector_type(16)));
typedef __bf16 v8bf __attribute__((ext_vector_type(8)));
typedef unsigned short ushortx4 __attribute__((ext_vector_type(4)));
typedef unsigned short ushortx8 __attribute__((ext_vector_type(8)));
typedef unsigned int uint4v __attribute__((ext_vector_type(4)));

#define NIMG 16
#define CCH  256
#define HWP  1600
#define PIT  776   // stage pitch (bf16 elems): 1552B, 16B aligned

__device__ __forceinline__ unsigned short f2bf(float f) {
  unsigned int u = __builtin_bit_cast(unsigned int, f);
  u = (u + 0x7FFFu + ((u >> 16) & 1u)) >> 16;
  return (unsigned short)u;
}

__device__ __forceinline__ f32x4 mfma16(v8bf a, v8bf b, f32x4 c) {
  return __builtin_amdgcn_mfma_f32_16x16x32_bf16(a, b, c, 0, 0, 0);
}

__device__ __forceinline__ unsigned cvtpk(float a, float b) {
  unsigned r;
  asm("v_cvt_pk_bf16_f32 %0, %1, %2" : "=v"(r) : "v"(a), "v"(b));
  return r;
}
#define PSWAP(a, b) asm("v_permlane32_swap_b32 %0, %1" : "+v"(a), "+v"(b))

// ---------------- kernel A: weight->bf16 + PE table ----------------
__global__ void prep_kernel(const float* __restrict__ qkv_w,
                            float* __restrict__ pe,
                            unsigned short* __restrict__ w_bf) {
  int tid = blockIdx.x * blockDim.x + threadIdx.x;
  int nthr = gridDim.x * blockDim.x;
  for (int i = tid; i < 768 * 256; i += nthr) w_bf[i] = f2bf(qkv_w[i]);
  const float c1 = 9.210340371976184f / 64.f;  // ln(10000)/64
  for (int i = tid; i < HWP * 256; i += nthr) {
    int p = i >> 8, c = i & 255;
    int j = p % 40, ii = p / 40;             // x = j (col), y = ii (row)
    int tt = c & 63;
    float omega = expf(-(float)tt * c1);
    float coord = (c < 128) ? (float)j : (float)ii;
    float a = coord * omega;
    pe[i] = ((c & 64) == 0) ? sinf(a) : cosf(a);
  }
}

// ---------------- kernel B: LN + QKV GEMM + PE ----------------
// outputs:
//   q_ws : [n][p][c] bf16, pre-scaled by 1/16 (attention scale folded in)
//   k_arr: frag-arranged: elem(n,db,kv,hi,e) at ((((n*16+db)*1600+kv)*2+hi)*8+e)
//          holds K[kv][d= db*16+hi*8+e]  -> QK A-frag loads coalesce
//   v_arr: frag-arranged: elem(n,kvs,hi,d,e) at ((((n*100+kvs)*2+hi)*256+d)*8+e)
//          holds V[kv= kvs*16+hi*8+e][d] -> PV A-frag (V^T) loads coalesce
__global__ __launch_bounds__(512, 2) void ln_qkv_kernel(
    const float* __restrict__ x, const float* __restrict__ ln_w, const float* __restrict__ ln_b,
    const unsigned short* __restrict__ w_bf, const float* __restrict__ qkv_b,
    const float* __restrict__ pe,
    unsigned short* __restrict__ q_ws, unsigned short* __restrict__ k_arr,
    unsigned short* __restrict__ v_arr) {
  __shared__ unsigned short buf[64][PIT];          // A-tile (cols 0..255) then qkv stage (0..767)
  __shared__ float red_s[8][64], red_q[8][64];
  __shared__ float mu_s[64], rs_s[64];

  int t = threadIdx.x;
  int n = blockIdx.x / 25, pt = blockIdx.x % 25;
  int pix0 = pt * 64;
  int p = t & 63, g = t >> 6;
  const float* xb = x + (size_t)n * CCH * HWP + pix0;

  // pass 1: LN stats (x kept in registers)
  float xv[32];
  float sum = 0.f, sq = 0.f;
#pragma unroll
  for (int i = 0; i < 32; ++i) {
    float v = xb[(size_t)(g * 32 + i) * HWP + p];
    xv[i] = v; sum += v; sq += v * v;
  }
  red_s[g][p] = sum; red_q[g][p] = sq;
  __syncthreads();
  if (t < 64) {
    float s = 0.f, q2 = 0.f;
#pragma unroll
    for (int gg = 0; gg < 8; ++gg) { s += red_s[gg][t]; q2 += red_q[gg][t]; }
    float mu = s * (1.f / 256.f);
    float var = q2 * (1.f / 256.f) - mu * mu;
    mu_s[t] = mu;
    rs_s[t] = rsqrtf(var + 1e-5f);
  }
  __syncthreads();
  float mu = mu_s[p], rs = rs_s[p];
#pragma unroll
  for (int i = 0; i < 32; ++i) {
    int cc = g * 32 + i;
    float xn = (xv[i] - mu) * rs * ln_w[cc] + ln_b[cc];
    buf[p][cc] = f2bf(xn);
  }
  __syncthreads();

  // GEMM: 64 pixels x 768 outs, K=256; 8 waves each own 96 output cols
  int w = t >> 6, l = t & 63, lr = l & 15, lg = l >> 4;
  int colbase = w * 96;
  f32x4 acc[4][6];
#pragma unroll
  for (int mi = 0; mi < 4; ++mi)
#pragma unroll
    for (int nf = 0; nf < 6; ++nf) acc[mi][nf] = (f32x4){0.f, 0.f, 0.f, 0.f};

#pragma unroll
  for (int ks = 0; ks < 8; ++ks) {
    v8bf aF[4];
#pragma unroll
    for (int mi = 0; mi < 4; ++mi)
      aF[mi] = *(const v8bf*)&buf[mi * 16 + lr][ks * 32 + lg * 8];
#pragma unroll
    for (int nf = 0; nf < 6; ++nf) {
      int o = colbase + nf * 16 + lr;
      v8bf bF = *(const v8bf*)&w_bf[o * 256 + ks * 32 + lg * 8];
#pragma unroll
      for (int mi = 0; mi < 4; ++mi) acc[mi][nf] = mfma16(aF[mi], bF, acc[mi][nf]);
    }
  }
  __syncthreads();  // A-tile dead; reuse buf as stage

  // epilogue: +bias, +PE on q/k, q pre-scaled by 1/16 (exact exponent shift)
#pragma unroll
  for (int nf = 0; nf < 6; ++nf) {
    int o = colbase + nf * 16 + lr;
    float bias = qkv_b[o];
#pragma unroll
    for (int mi = 0; mi < 4; ++mi) {
#pragma unroll
      for (int r = 0; r < 4; ++r) {
        int prow = mi * 16 + lg * 4 + r;
        float val = acc[mi][nf][r] + bias;
        if (o < 512) val += pe[(pix0 + prow) * 256 + (o & 255)];
        if (o < 256) val *= 0.0625f;
        buf[prow][o] = f2bf(val);
      }
    }
  }
  __syncthreads();

  // ---- q write: [n][p][c] ----
  size_t qbase = ((size_t)n * HWP + pix0) * 256;
#pragma unroll
  for (int it = 0; it < 4; ++it) {
    int id = t + it * 512;
    int row = id >> 5, cc = (id & 31) * 8;
    *(ushortx8*)&q_ws[qbase + row * 256 + cc] = *(const ushortx8*)&buf[row][cc];
  }
  // ---- k_arr write (frag-arranged) ----
  {
    int hi2 = t & 1, kvl = (t >> 1) & 63;
#pragma unroll
    for (int i = 0; i < 4; ++i) {
      int db = (t >> 7) + 4 * i;
      size_t di = (((size_t)n * 16 + db) * 1600 + pix0 + kvl) * 2 + hi2;
      *(ushortx8*)&k_arr[di * 8] = *(const ushortx8*)&buf[kvl][256 + db * 16 + hi2 * 8];
    }
  }
  // ---- v_arr write (frag-arranged) ----
  {
    int d = t & 255;
#pragma unroll
    for (int i = 0; i < 4; ++i) {
      int kh = (t >> 8) + 2 * i;        // 0..7
      int kvsl = kh >> 1, hi2 = kh & 1;
      ushortx8 vv;
#pragma unroll
      for (int e = 0; e < 8; ++e)
        vv[e] = buf[kvsl * 16 + hi2 * 8 + e][512 + d];
      size_t di = (((size_t)n * 100 + pt * 4 + kvsl) * 2 + hi2) * 256 + d;
      *(ushortx8*)&v_arr[di * 8] = vv;
    }
  }
}

// ---------------- kernel C: flash attention, 1 wave / 32 q rows, no LDS ----------------
__global__ __launch_bounds__(64, 1) void attn_kernel(
    const unsigned short* __restrict__ q_ws, const unsigned short* __restrict__ k_arr,
    const unsigned short* __restrict__ v_arr, const float* __restrict__ x,
    const float* __restrict__ gamma, float* __restrict__ out) {
  int l = threadIdx.x;
  int l31 = l & 31, hi = l >> 5;
  // XCD grouping: image n's 50 waves land on XCD n%8 (K+V of 2 images fit one L2)
  int slot = blockIdx.x & 7, j = blockIdx.x >> 3;
  int n = slot + 8 * (j / 50);
  int q0 = (j % 50) * 32;

  // Q fragments: B-frag Q^T[d][q], q = l31 (pre-scaled by 1/16)
  v8bf qf[16];
  {
    const unsigned short* qp = q_ws + ((size_t)n * HWP + q0 + l31) * 256 + hi * 8;
#pragma unroll
    for (int dt = 0; dt < 16; ++dt)
      qf[dt] = *(const v8bf*)(qp + dt * 16);
  }

  f32x16 acc[8];
#pragma unroll
  for (int dt = 0; dt < 8; ++dt)
#pragma unroll
    for (int r = 0; r < 16; ++r) acc[dt][r] = 0.f;

  float m_run = -1e30f, l_run = 0.f;

  const unsigned short* kbase = k_arr + (size_t)n * (16 * 1600 * 16);
  const unsigned short* vbase = v_arr + (size_t)n * (100 * 2 * 256 * 8);

  v8bf kA[16], kB[16];
#pragma unroll
  for (int dt = 0; dt < 16; ++dt)
    kA[dt] = *(const v8bf*)(kbase + (((size_t)dt * HWP + l31) * 2 + hi) * 8);

  auto body = [&](int kt, v8bf (&kc)[16], v8bf (&kn)[16]) {
    // S^T[kv][q] = K · Q^T   (two accumulation chains)
    f32x16 s0, s1;
#pragma unroll
    for (int r = 0; r < 16; ++r) { s0[r] = 0.f; s1[r] = 0.f; }
#pragma unroll
    for (int dt = 0; dt < 16; dt += 2) {
      s0 = __builtin_amdgcn_mfma_f32_32x32x16_bf16(kc[dt], qf[dt], s0, 0, 0, 0);
      s1 = __builtin_amdgcn_mfma_f32_32x32x16_bf16(kc[dt + 1], qf[dt + 1], s1, 0, 0, 0);
    }
    // prefetch next K tile (latency hides under softmax VALU)
    int ktn = (kt + 1 < 50) ? kt + 1 : 0;
#pragma unroll
    for (int dt = 0; dt < 16; ++dt)
      kn[dt] = *(const v8bf*)(kbase + (((size_t)dt * HWP + ktn * 32 + l31) * 2 + hi) * 8);

    // online softmax: lane l holds S rows kv=(r&3)+8*(r>>2)+4*hi for q=l31
    float p[16];
    float mx = -1e30f;
#pragma unroll
    for (int r = 0; r < 16; ++r) { p[r] = s0[r] + s1[r]; mx = fmaxf(mx, p[r]); }
    mx = fmaxf(mx, __shfl_xor(mx, 32));
    if (!__all(mx <= m_run)) {
      float mnew = fmaxf(m_run, mx);
      float alpha = __expf(m_run - mnew);
      l_run *= alpha;
#pragma unroll
      for (int dt = 0; dt < 8; ++dt)
#pragma unroll
        for (int r = 0; r < 16; ++r) acc[dt][r] *= alpha;
      m_run = mnew;
    }
    float sum = 0.f;
#pragma unroll
    for (int r = 0; r < 16; ++r) { p[r] = __expf(p[r] - m_run); sum += p[r]; }
    sum += __shfl_xor(sum, 32);
    l_run += sum;

    // P -> bf16 B-frags via cvt_pk + permlane32_swap (kv-slice j=0: p[0..7], j=1: p[8..15])
    unsigned x0 = cvtpk(p[0], p[1]), x1 = cvtpk(p[2], p[3]);
    unsigned y0 = cvtpk(p[4], p[5]), y1 = cvtpk(p[6], p[7]);
    PSWAP(x0, y0); PSWAP(x1, y1);
    uint4v u0 = {x0, x1, y0, y1};
    v8bf pf0 = __builtin_bit_cast(v8bf, u0);
    unsigned z0 = cvtpk(p[8], p[9]), z1 = cvtpk(p[10], p[11]);
    unsigned w0 = cvtpk(p[12], p[13]), w1 = cvtpk(p[14], p[15]);
    PSWAP(z0, w0); PSWAP(z1, w1);
    uint4v u1 = {z0, z1, w0, w1};
    v8bf pf1 = __builtin_bit_cast(v8bf, u1);

    // O^T[d][q] += V^T · P^T
#pragma unroll
    for (int dt = 0; dt < 8; ++dt) {
      v8bf v0 = *(const v8bf*)(vbase + ((((size_t)kt * 2 + 0) * 2 + hi) * 256 + dt * 32 + l31) * 8);
      v8bf v1 = *(const v8bf*)(vbase + ((((size_t)kt * 2 + 1) * 2 + hi) * 256 + dt * 32 + l31) * 8);
      acc[dt] = __builtin_amdgcn_mfma_f32_32x32x16_bf16(v0, pf0, acc[dt], 0, 0, 0);
      acc[dt] = __builtin_amdgcn_mfma_f32_32x32x16_bf16(v1, pf1, acc[dt], 0, 0, 0);
    }
  };

  for (int kt = 0; kt < 50; kt += 2) {
    body(kt, kA, kB);
    body(kt + 1, kB, kA);
  }

  // epilogue: out = x + gamma * O / l   (coalesced: lanes = consecutive q)
  float inv = 1.f / l_run;
  float gm = gamma[0];
#pragma unroll
  for (int dt = 0; dt < 8; ++dt) {
#pragma unroll
    for (int r = 0; r < 16; ++r) {
      int d = dt * 32 + (r & 3) + 8 * (r >> 2) + 4 * hi;
      size_t base = ((size_t)n * 256 + d) * HWP + q0 + l31;
      out[base] = x[base] + gm * acc[dt][r] * inv;
    }
  }
}

// ---------------- launcher ----------------
extern "C" void kernel_launch(void* const* d_in, const int* in_sizes, int n_in,
                              void* d_out, int out_size, void* d_ws, size_t ws_size,
                              hipStream_t stream) {
  const float* x     = (const float*)d_in[0];
  const float* ln_w  = (const float*)d_in[1];
  const float* ln_b  = (const float*)d_in[2];
  const float* qkv_w = (const float*)d_in[3];
  const float* qkv_b = (const float*)d_in[4];
  const float* gamma = (const float*)d_in[5];
  float* out = (float*)d_out;

  char* ws = (char*)d_ws;
  unsigned short* w_bf  = (unsigned short*)ws;             //   393,216 B
  float*          pe    = (float*)(ws + 393216);           // 1,638,400 B
  unsigned short* q_ws  = (unsigned short*)(ws + 2031616);   // 13,107,200 B
  unsigned short* k_arr = (unsigned short*)(ws + 15138816);  // 13,107,200 B
  unsigned short* v_arr = (unsigned short*)(ws + 28246016);  // 13,107,200 B

  hipLaunchKernelGGL(prep_kernel, dim3(384), dim3(256), 0, stream, qkv_w, pe, w_bf);
  hipLaunchKernelGGL(ln_qkv_kernel, dim3(400), dim3(512), 0, stream,
                     x, ln_w, ln_b, w_bf, qkv_b, pe, q_ws, k_arr, v_arr);
  hipLaunchKernelGGL(attn_kernel, dim3(800), dim3(64), 0, stream,
                     q_ws, k_arr, v_arr, x, gamma, out);
}

// Round 3
// 160.488 us; speedup vs baseline: 1.2455x; 1.1924x over previous
//
#include <hip/hip_runtime.h>
#include <hip/hip_bf16.h>

// ---------------- types ----------------
typedef float f32x4 __attribute__((ext_vector_type(4)));
typedef float f32x16 __attribute__((ext_vector_type(16)));
typedef __bf16 v8bf __attribute__((ext_vector_type(8)));
typedef unsigned short ushortx4 __attribute__((ext_vector_type(4)));
typedef unsigned short ushortx8 __attribute__((ext_vector_type(8)));
typedef unsigned int uint4v __attribute__((ext_vector_type(4)));

#define NIMG 16
#define CCH  256
#define HWP  1600
#define APIT 264   // A-tile pitch (bf16 elems): 528B = 33*16, 16B aligned, banks balanced

__device__ __forceinline__ unsigned short f2bf(float f) {
  unsigned int u = __builtin_bit_cast(unsigned int, f);
  u = (u + 0x7FFFu + ((u >> 16) & 1u)) >> 16;
  return (unsigned short)u;
}

__device__ __forceinline__ f32x4 mfma16(v8bf a, v8bf b, f32x4 c) {
  return __builtin_amdgcn_mfma_f32_16x16x32_bf16(a, b, c, 0, 0, 0);
}

__device__ __forceinline__ unsigned cvtpk(float a, float b) {
  unsigned r;
  asm("v_cvt_pk_bf16_f32 %0, %1, %2" : "=v"(r) : "v"(a), "v"(b));
  return r;
}
#define PSWAP(a, b) asm("v_permlane32_swap_b32 %0, %1" : "+v"(a), "+v"(b))

// ---------------- kernel A: weight->bf16 frag repack + PE table ----------------
// w_frag: A-frag layout for mfma16: elem(tile,ks,l,e) at ((tile*8+ks)*64+l)*8+e
//         holds W[o = tile*16 + (l&15)][c = ks*32 + (l>>4)*8 + e]
__global__ void prep_kernel(const float* __restrict__ qkv_w,
                            float* __restrict__ pe,
                            unsigned short* __restrict__ w_frag) {
  int tid = blockIdx.x * blockDim.x + threadIdx.x;
  int nthr = gridDim.x * blockDim.x;
  for (int i = tid; i < 768 * 256; i += nthr) {
    int o = i >> 8, c = i & 255;
    int tile = o >> 4, lr = o & 15;
    int ks = c >> 5, lg = (c >> 3) & 3, e = c & 7;
    w_frag[(((size_t)tile * 8 + ks) * 64 + lg * 16 + lr) * 8 + e] = f2bf(qkv_w[i]);
  }
  const float c1 = 9.210340371976184f / 64.f;  // ln(10000)/64
  for (int i = tid; i < HWP * 256; i += nthr) {
    int p = i >> 8, c = i & 255;
    int j = p % 40, ii = p / 40;             // x = j (col), y = ii (row)
    int tt = c & 63;
    float omega = expf(-(float)tt * c1);
    float coord = (c < 128) ? (float)j : (float)ii;
    float a = coord * omega;
    pe[i] = ((c & 64) == 0) ? sinf(a) : cosf(a);
  }
}

// ---------------- kernel B: LN + QKV GEMM + PE, direct frag-layout stores ----------------
// q_arr: elem(n,qt,dt,hi,l31,e) at ((((n*50+qt)*16+dt)*2+hi)*32+l31)*8+e
//        = Q[qt*32+l31][dt*16+hi*8+e] * 1/16  (attn B-frag, coalesced)
// k_arr: elem(n,dt,kv,hi,e) at (((n*16+dt)*1600+kv)*2+hi)*8+e
//        = K[kv][dt*16+hi*8+e]                (attn A-frag, coalesced)
// v_arr: elem(n,kvs,hi,d,e) at (((n*100+kvs)*2+hi)*256+d)*8+e
//        = V[kvs*16+hi*8+e][d]                (attn A-frag V^T, coalesced)
__global__ __launch_bounds__(512, 4) void ln_qkv_kernel(
    const float* __restrict__ x, const float* __restrict__ ln_w, const float* __restrict__ ln_b,
    const unsigned short* __restrict__ w_frag, const float* __restrict__ qkv_b,
    const float* __restrict__ pe,
    unsigned short* __restrict__ q_arr, unsigned short* __restrict__ k_arr,
    unsigned short* __restrict__ v_arr) {
  __shared__ unsigned short buf[64][APIT];     // 33.8 KB A-tile
  __shared__ float red_s[8][64], red_q[8][64];
  __shared__ float mu_s[64], rs_s[64];

  int t = threadIdx.x;
  int n = blockIdx.x / 25, pt = blockIdx.x % 25;
  int pix0 = pt * 64;
  int p = t & 63, g = t >> 6;
  const float* xb = x + (size_t)n * CCH * HWP + pix0;

  // pass 1: LN stats (x re-read in pass 2 from L2 -> no xv registers)
  {
    float sum = 0.f, sq = 0.f;
#pragma unroll
    for (int i = 0; i < 32; ++i) {
      float v = xb[(size_t)(g * 32 + i) * HWP + p];
      sum += v; sq += v * v;
    }
    red_s[g][p] = sum; red_q[g][p] = sq;
  }
  __syncthreads();
  if (t < 64) {
    float s = 0.f, q2 = 0.f;
#pragma unroll
    for (int gg = 0; gg < 8; ++gg) { s += red_s[gg][t]; q2 += red_q[gg][t]; }
    float mu = s * (1.f / 256.f);
    float var = q2 * (1.f / 256.f) - mu * mu;
    mu_s[t] = mu;
    rs_s[t] = rsqrtf(var + 1e-5f);
  }
  __syncthreads();
  {
    float mu = mu_s[p], rs = rs_s[p];
#pragma unroll
    for (int i4 = 0; i4 < 8; ++i4) {
      int c0 = g * 32 + i4 * 4;
      f32x4 lw = *(const f32x4*)&ln_w[c0];
      f32x4 lb = *(const f32x4*)&ln_b[c0];
      ushortx4 pk;
#pragma unroll
      for (int r = 0; r < 4; ++r) {
        float v = xb[(size_t)(c0 + r) * HWP + p];
        pk[r] = f2bf((v - mu) * rs * lw[r] + lb[r]);
      }
      *(ushortx4*)&buf[p][c0] = pk;
    }
  }
  __syncthreads();

  // GEMM: A = weights (frag-arranged global), B = x-tile (LDS)
  int w = t >> 6, l = t & 63, lr = l & 15, lg = l >> 4;
  f32x4 acc[6][4];
#pragma unroll
  for (int nf = 0; nf < 6; ++nf)
#pragma unroll
    for (int mi = 0; mi < 4; ++mi) acc[nf][mi] = (f32x4){0.f, 0.f, 0.f, 0.f};

#pragma unroll
  for (int ks = 0; ks < 8; ++ks) {
    v8bf bF[4];
#pragma unroll
    for (int mi = 0; mi < 4; ++mi)
      bF[mi] = *(const v8bf*)&buf[mi * 16 + lr][ks * 32 + lg * 8];
#pragma unroll
    for (int nf = 0; nf < 6; ++nf) {
      int tile = w + nf * 8;
      v8bf wf = *(const v8bf*)&w_frag[(((size_t)tile * 8 + ks) * 64 + l) * 8];
#pragma unroll
      for (int mi = 0; mi < 4; ++mi) acc[nf][mi] = mfma16(wf, bF[mi], acc[nf][mi]);
    }
  }

  // epilogue: acc[nf][mi][r] -> channel o = tile*16+lg*4+r, pixel pix0+mi*16+lr
  int lgh = lg >> 1, lgl = lg & 1;
  // ---- q (tiles 0..15): +bias +pe, *1/16, packed 8B stores ----
#pragma unroll
  for (int nf = 0; nf < 2; ++nf) {
    int tile = w + nf * 8;
    f32x4 bi = *(const f32x4*)&qkv_b[tile * 16 + lg * 4];
#pragma unroll
    for (int mi = 0; mi < 4; ++mi) {
      int pix = pix0 + mi * 16 + lr;
      f32x4 pev = *(const f32x4*)&pe[(size_t)pix * 256 + tile * 16 + lg * 4];
      f32x4 vv = (acc[nf][mi] + bi + pev) * 0.0625f;
      ushortx4 pk = {f2bf(vv[0]), f2bf(vv[1]), f2bf(vv[2]), f2bf(vv[3])};
      int qt = pix >> 5, l31 = pix & 31;
      size_t ad = ((((size_t)n * 50 + qt) * 16 + tile) * 2 + lgh) * 256 + l31 * 8 + lgl * 4;
      *(ushortx4*)&q_arr[ad] = pk;
    }
  }
  // ---- k (tiles 16..31): +bias +pe, packed 8B stores ----
#pragma unroll
  for (int nf = 2; nf < 4; ++nf) {
    int tile = w + nf * 8;
    int dt = tile - 16;
    f32x4 bi = *(const f32x4*)&qkv_b[tile * 16 + lg * 4];
#pragma unroll
    for (int mi = 0; mi < 4; ++mi) {
      int pix = pix0 + mi * 16 + lr;
      f32x4 pev = *(const f32x4*)&pe[(size_t)pix * 256 + dt * 16 + lg * 4];
      f32x4 vv = acc[nf][mi] + bi + pev;
      ushortx4 pk = {f2bf(vv[0]), f2bf(vv[1]), f2bf(vv[2]), f2bf(vv[3])};
      size_t ad = (((size_t)n * 16 + dt) * 1600 + pix) * 16 + lgh * 8 + lgl * 4;
      *(ushortx4*)&k_arr[ad] = pk;
    }
  }
  // ---- v (tiles 32..47): +bias, transposed scatter (2B stores, L2 merges) ----
#pragma unroll
  for (int nf = 4; nf < 6; ++nf) {
    int tile = w + nf * 8;
    f32x4 bi = *(const f32x4*)&qkv_b[tile * 16 + lg * 4];
#pragma unroll
    for (int mi = 0; mi < 4; ++mi) {
      int pix = pix0 + mi * 16 + lr;
      int kvs = pix >> 4, hi = (pix >> 3) & 1, e = pix & 7;
      f32x4 vv = acc[nf][mi] + bi;
      size_t vb = (((size_t)n * 100 + kvs) * 2 + hi) * 2048 + e;
      int d0 = (tile - 32) * 16 + lg * 4;
#pragma unroll
      for (int r = 0; r < 4; ++r)
        v_arr[vb + (size_t)(d0 + r) * 8] = f2bf(vv[r]);
    }
  }
}

// ---------------- kernel C: flash attention, 1 wave / 32 q rows, deep-pipelined ----------------
__global__ __launch_bounds__(64, 1) void attn_kernel(
    const unsigned short* __restrict__ q_arr, const unsigned short* __restrict__ k_arr,
    const unsigned short* __restrict__ v_arr, const float* __restrict__ x,
    const float* __restrict__ gamma, float* __restrict__ out) {
  int l = threadIdx.x;
  int l31 = l & 31, hi = l >> 5;
  // XCD grouping: image n's 50 waves land on XCD n%8 (K+V of 2 images fit one L2)
  int slot = blockIdx.x & 7, j = blockIdx.x >> 3;
  int n = slot + 8 * (j / 50);
  int qt = j % 50;
  int q0 = qt * 32;

  // Q B-frags (pre-scaled by 1/16), coalesced frag-layout loads
  v8bf qf[16];
  {
    const unsigned short* qp = q_arr + (((size_t)n * 50 + qt) * 32 + hi) * 256 + l31 * 8;
#pragma unroll
    for (int dt = 0; dt < 16; ++dt)
      qf[dt] = *(const v8bf*)(qp + dt * 512);
  }

  f32x16 acc[8];
#pragma unroll
  for (int dt = 0; dt < 8; ++dt)
#pragma unroll
    for (int r = 0; r < 16; ++r) acc[dt][r] = 0.f;

  float m_run = -1e30f, l_run = 0.f;

  const unsigned short* kbase = k_arr + (size_t)n * (16 * 1600 * 16);
  const unsigned short* vbase = v_arr + (size_t)n * (100 * 2 * 256 * 8);

  v8bf kA[16], kB[16];
#pragma unroll
  for (int dt = 0; dt < 16; ++dt)
    kA[dt] = *(const v8bf*)(kbase + dt * 25600 + l31 * 16 + hi * 8);

  auto body = [&](int kt, v8bf (&kc)[16], v8bf (&kn)[16]) {
    // V loads for THIS tile issued first: consumed after QK+softmax (~500 cyc slack)
    v8bf vf0[8], vf1[8];
    {
      const unsigned short* vp = vbase + (size_t)kt * 8192 + hi * 2048 + l31 * 8;
#pragma unroll
      for (int dt = 0; dt < 8; ++dt) vf0[dt] = *(const v8bf*)(vp + dt * 256);
#pragma unroll
      for (int dt = 0; dt < 8; ++dt) vf1[dt] = *(const v8bf*)(vp + 4096 + dt * 256);
    }
    // S^T[kv][q] = K · Q^T
    f32x16 s0, s1;
#pragma unroll
    for (int r = 0; r < 16; ++r) { s0[r] = 0.f; s1[r] = 0.f; }
#pragma unroll
    for (int dt = 0; dt < 16; dt += 2) {
      s0 = __builtin_amdgcn_mfma_f32_32x32x16_bf16(kc[dt], qf[dt], s0, 0, 0, 0);
      s1 = __builtin_amdgcn_mfma_f32_32x32x16_bf16(kc[dt + 1], qf[dt + 1], s1, 0, 0, 0);
    }
    // prefetch next K tile (full-body slack)
    int ktn = (kt + 1 < 50) ? kt + 1 : 0;
#pragma unroll
    for (int dt = 0; dt < 16; ++dt)
      kn[dt] = *(const v8bf*)(kbase + dt * 25600 + (ktn * 32 + l31) * 16 + hi * 8);

    // online softmax: lane holds S rows kv=(r&3)+8*(r>>2)+4*hi for q=l31
    float p[16];
#pragma unroll
    for (int r = 0; r < 16; ++r) p[r] = s0[r] + s1[r];
    float t0 = fmaxf(p[0], p[1]), t1 = fmaxf(p[2], p[3]);
    float t2 = fmaxf(p[4], p[5]), t3 = fmaxf(p[6], p[7]);
    float t4 = fmaxf(p[8], p[9]), t5 = fmaxf(p[10], p[11]);
    float t6 = fmaxf(p[12], p[13]), t7 = fmaxf(p[14], p[15]);
    float mx = fmaxf(fmaxf(fmaxf(t0, t1), fmaxf(t2, t3)),
                     fmaxf(fmaxf(t4, t5), fmaxf(t6, t7)));
    mx = fmaxf(mx, __shfl_xor(mx, 32));
    if (!__all(mx <= m_run + 4.f)) {        // defer-rescale threshold (e^4 headroom)
      float mnew = fmaxf(m_run, mx);
      float alpha = __expf(m_run - mnew);
      l_run *= alpha;
#pragma unroll
      for (int dt = 0; dt < 8; ++dt)
#pragma unroll
        for (int r = 0; r < 16; ++r) acc[dt][r] *= alpha;
      m_run = mnew;
    }
    float sum = 0.f;
#pragma unroll
    for (int r = 0; r < 16; ++r) { p[r] = __expf(p[r] - m_run); sum += p[r]; }
    sum += __shfl_xor(sum, 32);
    l_run += sum;

    // P -> bf16 B-frags via cvt_pk + permlane32_swap
    unsigned x0 = cvtpk(p[0], p[1]), x1 = cvtpk(p[2], p[3]);
    unsigned y0 = cvtpk(p[4], p[5]), y1 = cvtpk(p[6], p[7]);
    PSWAP(x0, y0); PSWAP(x1, y1);
    uint4v u0 = {x0, x1, y0, y1};
    v8bf pf0 = __builtin_bit_cast(v8bf, u0);
    unsigned z0 = cvtpk(p[8], p[9]), z1 = cvtpk(p[10], p[11]);
    unsigned w0 = cvtpk(p[12], p[13]), w1 = cvtpk(p[14], p[15]);
    PSWAP(z0, w0); PSWAP(z1, w1);
    uint4v u1 = {z0, z1, w0, w1};
    v8bf pf1 = __builtin_bit_cast(v8bf, u1);

    // O^T[d][q] += V^T · P^T
#pragma unroll
    for (int dt = 0; dt < 8; ++dt) {
      acc[dt] = __builtin_amdgcn_mfma_f32_32x32x16_bf16(vf0[dt], pf0, acc[dt], 0, 0, 0);
      acc[dt] = __builtin_amdgcn_mfma_f32_32x32x16_bf16(vf1[dt], pf1, acc[dt], 0, 0, 0);
    }
  };

  for (int kt = 0; kt < 50; kt += 2) {
    body(kt, kA, kB);
    body(kt + 1, kB, kA);
  }

  // epilogue: out = x + gamma * O / l   (coalesced: lanes = consecutive q)
  float inv = 1.f / l_run;
  float gm = gamma[0];
#pragma unroll
  for (int dt = 0; dt < 8; ++dt) {
#pragma unroll
    for (int r = 0; r < 16; ++r) {
      int d = dt * 32 + (r & 3) + 8 * (r >> 2) + 4 * hi;
      size_t base = ((size_t)n * 256 + d) * HWP + q0 + l31;
      out[base] = x[base] + gm * acc[dt][r] * inv;
    }
  }
}

// ---------------- launcher ----------------
extern "C" void kernel_launch(void* const* d_in, const int* in_sizes, int n_in,
                              void* d_out, int out_size, void* d_ws, size_t ws_size,
                              hipStream_t stream) {
  const float* x     = (const float*)d_in[0];
  const float* ln_w  = (const float*)d_in[1];
  const float* ln_b  = (const float*)d_in[2];
  const float* qkv_w = (const float*)d_in[3];
  const float* qkv_b = (const float*)d_in[4];
  const float* gamma = (const float*)d_in[5];
  float* out = (float*)d_out;

  char* ws = (char*)d_ws;
  unsigned short* w_frag = (unsigned short*)ws;              //   393,216 B
  float*          pe     = (float*)(ws + 393216);            // 1,638,400 B
  unsigned short* q_arr  = (unsigned short*)(ws + 2031616);    // 13,107,200 B
  unsigned short* k_arr  = (unsigned short*)(ws + 15138816);   // 13,107,200 B
  unsigned short* v_arr  = (unsigned short*)(ws + 28246016);   // 13,107,200 B

  hipLaunchKernelGGL(prep_kernel, dim3(384), dim3(256), 0, stream, qkv_w, pe, w_frag);
  hipLaunchKernelGGL(ln_qkv_kernel, dim3(400), dim3(512), 0, stream,
                     x, ln_w, ln_b, w_frag, qkv_b, pe, q_arr, k_arr, v_arr);
  hipLaunchKernelGGL(attn_kernel, dim3(800), dim3(64), 0, stream,
                     q_arr, k_arr, v_arr, x, gamma, out);
}